// Round 10
// baseline (112.525 us; speedup 1.0000x reference)
//
#include <hip/hip_runtime.h>
#include <math.h>

#define BB 2048
#define T  200
#define H  64
#define H1 80
#define H2 40
#define BT (BB * T)          // 409600

typedef __attribute__((ext_vector_type(8))) short short8;
typedef __attribute__((ext_vector_type(4))) short s4v;
typedef __attribute__((ext_vector_type(4))) float floatx4;

// ws byte offsets (computed host-side, passed as distinct restrict pointers):
//   w1p : ushort[80*128]   @ 0        (20480 B)
//   w2b : ushort[3840]     @ 20480    ( 7680 B)
//   qh  : float [2048*80]  @ 28160    (655360 B)
//   sc  : float [2048*256] @ 683520   (2097152 B)
//   kb  : ushort[BT*64]    @ 2780672  (52428800 B)

__device__ __forceinline__ unsigned short f2b(float x) {
    union { float f; unsigned u; } v; v.f = x;
    unsigned r = v.u + 0x7FFF + ((v.u >> 16) & 1);   // RNE (finite inputs only)
    return (unsigned short)(r >> 16);
}
__device__ __forceinline__ float b2f(unsigned short u) {
    union { unsigned u; float f; } v; v.u = ((unsigned)u) << 16;
    return v.f;
}

__device__ __forceinline__ floatx4 mfma16(s4v a, s4v b, floatx4 c) {
#if __has_builtin(__builtin_amdgcn_mfma_f32_16x16x16bf16_1k)
    return __builtin_amdgcn_mfma_f32_16x16x16bf16_1k(a, b, c, 0, 0, 0);
#else
    floatx4 d;
    asm volatile("s_nop 1\n\t"
                 "v_mfma_f32_16x16x16_bf16 %0, %1, %2, %3\n\t"
                 "s_nop 7\n\ts_nop 4"
                 : "=v"(d) : "v"(a), "v"(b), "v"(c));
    return d;
#endif
}

// ---------------- prep: W1' bf16, W2 B-frag table, qh[b][f] ----------------
__global__ __launch_bounds__(256)
void prep_kernel(const float* __restrict__ W1, const float* __restrict__ W2,
                 const float* __restrict__ b1, const float* __restrict__ query,
                 unsigned short* __restrict__ w1p,
                 unsigned short* __restrict__ w2b,
                 float* __restrict__ qh) {
    int gid = blockIdx.x * 256 + threadIdx.x;      // 0 .. 163839
    if (gid < H1 * 128) {                          // W' = [Wk - Wm ; Wp]  [f][k]
        int f = gid >> 7, k = gid & 127;
        float v = (k < H) ? W1[(64 + k) * H1 + f] - W1[(128 + k) * H1 + f]
                          : W1[(192 + (k - 64)) * H1 + f];
        w1p[gid] = f2b(v);
    }
    if (gid < 3840) {                              // W2 B-frags for 16x16x16
        int j = gid & 3, lane = (gid >> 2) & 63, tk = gid >> 8;   // tk 0..14
        int nt = tk / 5, kk = tk - nt * 5;
        int f = kk * 16 + (lane >> 4) * 4 + j;     // k index of frag elem
        int g = nt * 16 + (lane & 15);             // n index
        float v = (g < H2) ? W2[f * H2 + g] : 0.f;
        w2b[gid] = f2b(v);
    }
    // qh[b][f] = b1[f] + q[b] @ (Wq + Wm)
    int b = gid / H1, f = gid - b * H1;
    const float* q = query + (size_t)b * H;
    float acc = b1[f];
    #pragma unroll 8
    for (int h = 0; h < H; ++h)
        acc += q[h] * (W1[h * H1 + f] + W1[(128 + h) * H1 + f]);
    qh[gid] = acc;
}

// ------- scores: barrier-free, LDS-free; 64 bt-rows per 256-thr block -------
__global__ __launch_bounds__(256, 4)
void score_kernel(const float* __restrict__ query,
                  const float* __restrict__ keys,
                  const float* __restrict__ b2,
                  const float* __restrict__ Wfc,
                  const float* __restrict__ bfc,
                  const unsigned short* __restrict__ w1p,
                  const unsigned short* __restrict__ w2b,
                  const float* __restrict__ qh,
                  float* __restrict__ sc,
                  unsigned short* __restrict__ kbuf)
{
    const int tid = threadIdx.x;
    const int wv = tid >> 6, ln = tid & 63;
    const int lrow = ln & 15, g16 = ln >> 4, lk8 = g16 * 8;
    const int bt0w = blockIdx.x * 64 + wv * 16;    // wave's 16 t-rows
    const int t_lane = bt0w + lrow;                // this lane's key row
    const int b_lane = t_lane / T;

    // ---- issue key/q loads (32B contiguous per lane per ks) ----
    const float4* krow4 = reinterpret_cast<const float4*>(keys + (size_t)t_lane * H);
    const float4* qrow4 = reinterpret_cast<const float4*>(query + (size_t)b_lane * H);
    float4 k00 = krow4[g16 * 2],     k01 = krow4[g16 * 2 + 1];
    float4 k10 = krow4[8 + g16 * 2], k11 = krow4[8 + g16 * 2 + 1];
    float4 q00 = qrow4[g16 * 2],     q01 = qrow4[g16 * 2 + 1];
    float4 q10 = qrow4[8 + g16 * 2], q11 = qrow4[8 + g16 * 2 + 1];

    // ---- hoist stage-2 weight frags (independent, L1/L2) ----
    const s4v* w2bv = reinterpret_cast<const s4v*>(w2b);
    s4v b4[3][5];
    #pragma unroll
    for (int nt = 0; nt < 3; ++nt)
        #pragma unroll
        for (int kk = 0; kk < 5; ++kk)
            b4[nt][kk] = w2bv[(nt * 5 + kk) * 64 + ln];
    float wfcv[3], b2v[3];
    #pragma unroll
    for (int nt = 0; nt < 3; ++nt) {
        int g = nt * 16 + lrow;
        wfcv[nt] = (g < H2) ? Wfc[g] : 0.f;
        b2v[nt]  = (g < H2) ? b2[g]  : 0.f;
    }
    float bfc0 = bfc[0];

    // ---- convert to bf16 fragments ----
    short8 af[2], af23[2];
    af[0][0] = (short)f2b(k00.x);  af23[0][0] = (short)f2b(k00.x * q00.x);
    af[0][1] = (short)f2b(k00.y);  af23[0][1] = (short)f2b(k00.y * q00.y);
    af[0][2] = (short)f2b(k00.z);  af23[0][2] = (short)f2b(k00.z * q00.z);
    af[0][3] = (short)f2b(k00.w);  af23[0][3] = (short)f2b(k00.w * q00.w);
    af[0][4] = (short)f2b(k01.x);  af23[0][4] = (short)f2b(k01.x * q01.x);
    af[0][5] = (short)f2b(k01.y);  af23[0][5] = (short)f2b(k01.y * q01.y);
    af[0][6] = (short)f2b(k01.z);  af23[0][6] = (short)f2b(k01.z * q01.z);
    af[0][7] = (short)f2b(k01.w);  af23[0][7] = (short)f2b(k01.w * q01.w);
    af[1][0] = (short)f2b(k10.x);  af23[1][0] = (short)f2b(k10.x * q10.x);
    af[1][1] = (short)f2b(k10.y);  af23[1][1] = (short)f2b(k10.y * q10.y);
    af[1][2] = (short)f2b(k10.z);  af23[1][2] = (short)f2b(k10.z * q10.z);
    af[1][3] = (short)f2b(k10.w);  af23[1][3] = (short)f2b(k10.w * q10.w);
    af[1][4] = (short)f2b(k11.x);  af23[1][4] = (short)f2b(k11.x * q11.x);
    af[1][5] = (short)f2b(k11.y);  af23[1][5] = (short)f2b(k11.y * q11.y);
    af[1][6] = (short)f2b(k11.z);  af23[1][6] = (short)f2b(k11.z * q11.z);
    af[1][7] = (short)f2b(k11.w);  af23[1][7] = (short)f2b(k11.w * q11.w);

    // spill bf16 keys for attn_out (restrict: does not order vs weight loads)
    *reinterpret_cast<short8*>(&kbuf[(size_t)t_lane * 64 + lk8])      = af[0];
    *reinterpret_cast<short8*>(&kbuf[(size_t)t_lane * 64 + 32 + lk8]) = af[1];

    // ---- stage 1 (swapped operands): lane holds hid[t_lane][4 f's] per mt ----
    const float* qhb = qh + b_lane * H1;
    unsigned pk[5][2];
    #pragma unroll
    for (int mt = 0; mt < 5; ++mt) {
        const unsigned short* wr = w1p + (mt * 16 + lrow) * 128;   // A row = f
        short8 bf0 = *reinterpret_cast<const short8*>(wr + lk8);
        short8 bf1 = *reinterpret_cast<const short8*>(wr + 32 + lk8);
        short8 bf2 = *reinterpret_cast<const short8*>(wr + 64 + lk8);
        short8 bf3 = *reinterpret_cast<const short8*>(wr + 96 + lk8);
        floatx4 acc = {0.f, 0.f, 0.f, 0.f};
        acc = __builtin_amdgcn_mfma_f32_16x16x32_bf16(bf0, af[0],   acc, 0, 0, 0);
        acc = __builtin_amdgcn_mfma_f32_16x16x32_bf16(bf1, af[1],   acc, 0, 0, 0);
        acc = __builtin_amdgcn_mfma_f32_16x16x32_bf16(bf2, af23[0], acc, 0, 0, 0);
        acc = __builtin_amdgcn_mfma_f32_16x16x32_bf16(bf3, af23[1], acc, 0, 0, 0);
        int fb = mt * 16 + g16 * 4;                 // D row = f = mt*16+g16*4+r
        float r0 = fmaxf(acc[0] + qhb[fb + 0], 0.f);
        float r1 = fmaxf(acc[1] + qhb[fb + 1], 0.f);
        float r2 = fmaxf(acc[2] + qhb[fb + 2], 0.f);
        float r3 = fmaxf(acc[3] + qhb[fb + 3], 0.f);
        pk[mt][0] = (unsigned)f2b(r0) | ((unsigned)f2b(r1) << 16);
        pk[mt][1] = (unsigned)f2b(r2) | ((unsigned)f2b(r3) << 16);
    }

    // ---- stage 2: 16x16x16 MFMAs; pk[kk] IS the A-frag for k-step kk ----
    float vsum[4] = {0.f, 0.f, 0.f, 0.f};
    #pragma unroll
    for (int nt = 0; nt < 3; ++nt) {
        floatx4 acc = {0.f, 0.f, 0.f, 0.f};
        #pragma unroll
        for (int kk = 0; kk < 5; ++kk) {
            union { unsigned u[2]; s4v s; } ua;
            ua.u[0] = pk[kk][0]; ua.u[1] = pk[kk][1];
            acc = mfma16(ua.s, b4[nt][kk], acc);
        }
        #pragma unroll
        for (int r = 0; r < 4; ++r)
            vsum[r] += fmaxf(acc[r] + b2v[nt], 0.f) * wfcv[nt];
    }
    #pragma unroll
    for (int r = 0; r < 4; ++r) {
        vsum[r] += __shfl_xor(vsum[r], 1);
        vsum[r] += __shfl_xor(vsum[r], 2);
        vsum[r] += __shfl_xor(vsum[r], 4);
        vsum[r] += __shfl_xor(vsum[r], 8);
    }
    if (lrow == 0) {
        #pragma unroll
        for (int r = 0; r < 4; ++r) {
            int t = bt0w + g16 * 4 + r;            // D2 row = t-local
            int bR = t / T, tR = t - bR * T;
            sc[bR * 256 + tR] = (vsum[r] + bfc0) * 0.125f;
        }
    }
}

// ---------------- softmax + weighted key sum (bf16 keys from ws) ----------------
__global__ __launch_bounds__(256)
void attn_out_kernel(const int* __restrict__ keys_length,
                     const float* __restrict__ sc,
                     const unsigned short* __restrict__ kbuf,
                     float* __restrict__ out)
{
    __shared__ float sS[256];
    __shared__ float sRed[8];
    __shared__ float sOutp[4][64];
    const int b = blockIdx.x;
    const int tid = threadIdx.x;
    const int wv = tid >> 6, ln = tid & 63;
    const int len = keys_length[b];

    float s = -INFINITY;
    if (tid < len) s = sc[b * 256 + tid];
    float m = s;
    #pragma unroll
    for (int off = 32; off > 0; off >>= 1) m = fmaxf(m, __shfl_xor(m, off));
    if (ln == 0) sRed[wv] = m;
    __syncthreads();
    float mx = fmaxf(fmaxf(sRed[0], sRed[1]), fmaxf(sRed[2], sRed[3]));
    float e = (tid < len) ? __expf(s - mx) : 0.f;
    sS[tid] = e;
    float sum = e;
    #pragma unroll
    for (int off = 32; off > 0; off >>= 1) sum += __shfl_xor(sum, off);
    if (ln == 0) sRed[4 + wv] = sum;
    __syncthreads();
    float denom = (sRed[4] + sRed[5]) + (sRed[6] + sRed[7]);
    float inv = 1.f / denom;

    const unsigned short* kbu = kbuf + (size_t)b * T * 64;
    const int c = tid & 7;          // 8-bf16 chunk (h = c*8 .. c*8+7)
    const int rg = tid >> 3;        // 0..31 row group
    float acc[8];
    #pragma unroll
    for (int j = 0; j < 8; ++j) acc[j] = 0.f;
    #pragma unroll
    for (int k = 0; k < 7; ++k) {
        int t = rg + (k << 5);
        if (t < T) {
            float w = sS[t];
            uint4 v = *reinterpret_cast<const uint4*>(&kbu[t * 64 + c * 8]);
            acc[0] += w * b2f((unsigned short)(v.x & 0xffff));
            acc[1] += w * b2f((unsigned short)(v.x >> 16));
            acc[2] += w * b2f((unsigned short)(v.y & 0xffff));
            acc[3] += w * b2f((unsigned short)(v.y >> 16));
            acc[4] += w * b2f((unsigned short)(v.z & 0xffff));
            acc[5] += w * b2f((unsigned short)(v.z >> 16));
            acc[6] += w * b2f((unsigned short)(v.w & 0xffff));
            acc[7] += w * b2f((unsigned short)(v.w >> 16));
        }
    }
    #pragma unroll
    for (int j = 0; j < 8; ++j) {
        acc[j] += __shfl_xor(acc[j], 8);
        acc[j] += __shfl_xor(acc[j], 16);
        acc[j] += __shfl_xor(acc[j], 32);
    }
    if (ln < 8) {
        float4 v0, v1;
        v0.x = acc[0]; v0.y = acc[1]; v0.z = acc[2]; v0.w = acc[3];
        v1.x = acc[4]; v1.y = acc[5]; v1.z = acc[6]; v1.w = acc[7];
        *reinterpret_cast<float4*>(&sOutp[wv][ln * 8])     = v0;
        *reinterpret_cast<float4*>(&sOutp[wv][ln * 8 + 4]) = v1;
    }
    __syncthreads();
    if (tid < H) {
        float o = (sOutp[0][tid] + sOutp[1][tid]) + (sOutp[2][tid] + sOutp[3][tid]);
        out[(size_t)b * H + tid] = o * inv;
    }
}

extern "C" void kernel_launch(void* const* d_in, const int* in_sizes, int n_in,
                              void* d_out, int out_size, void* d_ws, size_t ws_size,
                              hipStream_t stream) {
    const float* query       = (const float*)d_in[0];
    const float* keys        = (const float*)d_in[1];
    const int*   keys_length = (const int*)  d_in[2];
    const float* W1          = (const float*)d_in[3];
    const float* b1          = (const float*)d_in[4];
    const float* W2          = (const float*)d_in[5];
    const float* b2          = (const float*)d_in[6];
    const float* Wfc         = (const float*)d_in[7];
    const float* bfc         = (const float*)d_in[8];
    float* out = (float*)d_out;
    char*  wsb = (char*)d_ws;

    unsigned short* w1p  = (unsigned short*)(wsb);             // 20480 B
    unsigned short* w2b  = (unsigned short*)(wsb + 20480);     //  7680 B
    float*          qh   = (float*)         (wsb + 28160);     // 655360 B
    float*          sc   = (float*)         (wsb + 683520);    // 2097152 B
    unsigned short* kbuf = (unsigned short*)(wsb + 2780672);   // 52428800 B

    prep_kernel<<<640, 256, 0, stream>>>(W1, W2, b1, query, w1p, w2b, qh);
    score_kernel<<<BT / 64, 256, 0, stream>>>(query, keys, b2, Wfc, bfc,
                                              w1p, w2b, qh, sc, kbuf);
    attn_out_kernel<<<BB, 256, 0, stream>>>(keys_length, sc, kbuf, out);
}

// Round 11
// 112.143 us; speedup vs baseline: 1.0034x; 1.0034x over previous
//
#include <hip/hip_runtime.h>
#include <math.h>

#define BB 2048
#define T  200
#define H  64
#define H1 80
#define H2 40
#define BT (BB * T)          // 409600
#define TILE 128
#define NBLK (BT / TILE)     // 3200

typedef __attribute__((ext_vector_type(8))) short short8;
typedef __attribute__((ext_vector_type(4))) float floatx4;

// ws byte layout (host passes distinct restrict pointers):
//   w1p : ushort[80*128]     @ 0         (20480 B)  W' = [Wk-Wm ; Wp], [f][k]
//   w2t : ushort[48*104]     @ 20480     ( 9984 B)  W2^T padded [g][k]
//   qh  : float [2048*80]    @ 30464     (655360 B)
//   sc  : float [2048*256]   @ 685824    (2097152 B)
//   kbuf: ushort[BT*64]      @ 2782976   (52428800 B)

__device__ __forceinline__ unsigned short f2b(float x) {
    union { float f; unsigned u; } v; v.f = x;
    unsigned r = v.u + 0x7FFF + ((v.u >> 16) & 1);   // RNE (finite inputs only)
    return (unsigned short)(r >> 16);
}
__device__ __forceinline__ float b2f(unsigned short u) {
    union { unsigned u; float f; } v; v.u = ((unsigned)u) << 16;
    return v.f;
}

// ---------------- prep: W1' bf16, W2^T bf16, qh[b][f] ----------------
__global__ __launch_bounds__(256)
void prep_kernel(const float* __restrict__ W1, const float* __restrict__ W2,
                 const float* __restrict__ b1, const float* __restrict__ query,
                 unsigned short* __restrict__ w1p,
                 unsigned short* __restrict__ w2t,
                 float* __restrict__ qh) {
    int gid = blockIdx.x * 256 + threadIdx.x;      // 0 .. 163839
    if (gid < H1 * 128) {                          // W' = [Wk - Wm ; Wp]  [f][k]
        int f = gid >> 7, k = gid & 127;
        float v = (k < H) ? W1[(64 + k) * H1 + f] - W1[(128 + k) * H1 + f]
                          : W1[(192 + (k - 64)) * H1 + f];
        w1p[gid] = f2b(v);
    }
    if (gid < 48 * 104) {                          // W2^T padded [g][k]
        int n = gid / 104, k = gid % 104;
        float v = (n < H2 && k < H1) ? W2[k * H2 + n] : 0.f;
        w2t[gid] = f2b(v);
    }
    // qh[b][f] = b1[f] + q[b] @ (Wq + Wm)
    int b = gid / H1, f = gid - b * H1;
    const float* q = query + (size_t)b * H;
    float acc = b1[f];
    #pragma unroll 8
    for (int h = 0; h < H; ++h)
        acc += q[h] * (W1[h * H1 + f] + W1[(128 + h) * H1 + f]);
    qh[gid] = acc;
}

// ---------------- scores: 128-row tiles, LDS keys + per-wave scratch ----------------
__global__ __launch_bounds__(512, 4)
void score_kernel(const float* __restrict__ query,
                  const float* __restrict__ keys,
                  const float* __restrict__ b2,
                  const float* __restrict__ Wfc,
                  const float* __restrict__ bfc,
                  const unsigned short* __restrict__ w1p,
                  const unsigned short* __restrict__ w2t,
                  const float* __restrict__ qh,
                  float* __restrict__ sc,
                  unsigned short* __restrict__ kbuf)
{
    // sAS: A-tile keys (128 rows x 64 ushort, swizzled; 16384 B) UNION
    //      per-wave hid scratch (8 x 16 x 104 ushort = 26624 B)
    __shared__ unsigned short sAS[13312];
    __shared__ unsigned short sQb[128];        // bf16 q rows for b0, b0+1
    __shared__ float sQh2[160];                // qh rows for b0, b0+1

    const int tid = threadIdx.x;
    const int wv = tid >> 6, ln = tid & 63;
    const int lrow = ln & 15;
    const int lk8 = (ln >> 4) * 8;
    const int bt0 = blockIdx.x * TILE;
    const int b0 = bt0 / T;
    const int bsplit = (b0 + 1) * T;
    const int bnext = (b0 + 1 < BB) ? b0 + 1 : b0;

    // ---- stage A-tile: keys f32 -> bf16 LDS (swizzled) + bf16 spill to kbuf ----
    const float4* kb4 = reinterpret_cast<const float4*>(keys) + (size_t)bt0 * (H / 4);
    #pragma unroll
    for (int kk = 0; kk < 4; ++kk) {
        int idx = tid + (kk << 9);                 // 0..2047
        float4 v = kb4[idx];
        int row = idx >> 4, seg = idx & 15;
        int chunk = seg >> 1, half = seg & 1;
        uint2 p;
        p.x = (unsigned)f2b(v.x) | ((unsigned)f2b(v.y) << 16);
        p.y = (unsigned)f2b(v.z) | ((unsigned)f2b(v.w) << 16);
        *reinterpret_cast<uint2*>(
            &sAS[row * 64 + ((chunk ^ (row & 7)) << 3) + (half << 2)]) = p;
        *reinterpret_cast<uint2*>(
            &kbuf[((size_t)(bt0 + row)) * 64 + (seg << 2)]) = p;
    }
    if (tid < 128) {                               // q rows as bf16
        int which = tid >> 6, h = tid & 63;
        int bq = which ? bnext : b0;
        sQb[tid] = f2b(query[(size_t)bq * H + h]);
    }
    if (tid < 160) {                               // qh rows
        int which = (tid >= 80), f = tid - which * 80;
        int bq = which ? bnext : b0;
        sQh2[tid] = qh[bq * H1 + f];
    }
    __syncthreads();

    // ---- hoist A k-frags; build q*k frags in-register ----
    const int mrow = wv * 16 + lrow;
    const int selL = (bt0 + mrow >= bsplit) ? 1 : 0;
    short8 af[2], af23[2];
    #pragma unroll
    for (int ks = 0; ks < 2; ++ks) {
        int c = ks * 4 + (ln >> 4);
        af[ks] = *reinterpret_cast<const short8*>(
            &sAS[mrow * 64 + ((c ^ (mrow & 7)) << 3)]);
        short8 aq = *reinterpret_cast<const short8*>(&sQb[selL * 64 + ks * 32 + lk8]);
        #pragma unroll
        for (int j = 0; j < 8; ++j)
            af23[ks][j] = (short)f2b(
                b2f((unsigned short)af[ks][j]) * b2f((unsigned short)aq[j]));
    }
    __syncthreads();   // all af reads done before scratch overwrites sAS

    // ---- per-wave hid scratch; zero K-pad cols 80..95 ----
    unsigned short* scr = &sAS[wv * 1664];
    {
        uint2 z; z.x = 0; z.y = 0;
        *reinterpret_cast<uint2*>(&scr[(ln >> 2) * 104 + 80 + (ln & 3) * 4]) = z;
    }

    // ---- stage 1: hid[16][80] = ReLU([k, q*k] @ W' + qh); B-frags via L1 ----
    const int rb = (ln >> 4) * 4;
    #pragma unroll
    for (int nt = 0; nt < 5; ++nt) {
        int brow = nt * 16 + lrow;
        const unsigned short* wrow = &w1p[brow * 128];
        short8 bf0 = *reinterpret_cast<const short8*>(&wrow[lk8]);
        short8 bf1 = *reinterpret_cast<const short8*>(&wrow[32 + lk8]);
        short8 bf2 = *reinterpret_cast<const short8*>(&wrow[64 + lk8]);
        short8 bf3 = *reinterpret_cast<const short8*>(&wrow[96 + lk8]);
        floatx4 acc = {0.f, 0.f, 0.f, 0.f};
        acc = __builtin_amdgcn_mfma_f32_16x16x32_bf16(af[0],   bf0, acc, 0, 0, 0);
        acc = __builtin_amdgcn_mfma_f32_16x16x32_bf16(af[1],   bf1, acc, 0, 0, 0);
        acc = __builtin_amdgcn_mfma_f32_16x16x32_bf16(af23[0], bf2, acc, 0, 0, 0);
        acc = __builtin_amdgcn_mfma_f32_16x16x32_bf16(af23[1], bf3, acc, 0, 0, 0);
        #pragma unroll
        for (int r = 0; r < 4; ++r) {
            int sel = (bt0 + wv * 16 + rb + r >= bsplit) ? 1 : 0;
            float qhv = sQh2[sel * 80 + nt * 16 + lrow];
            scr[(rb + r) * 104 + nt * 16 + lrow] = f2b(fmaxf(acc[r] + qhv, 0.f));
        }
    }

    // ---- stage 2: scores = relu(hid @ W2 + b2) . Wfc (w2t frags via L1) ----
    float bfc0 = bfc[0];
    short8 a2[3];
    #pragma unroll
    for (int ks = 0; ks < 3; ++ks)
        a2[ks] = *reinterpret_cast<const short8*>(&scr[lrow * 104 + ks * 32 + lk8]);
    floatx4 vsum = {0.f, 0.f, 0.f, 0.f};
    #pragma unroll
    for (int nt = 0; nt < 3; ++nt) {
        int g = nt * 16 + lrow;
        float wf = (g < H2) ? Wfc[g] : 0.f;
        float bb = (g < H2) ? b2[g] : 0.f;
        floatx4 acc = {0.f, 0.f, 0.f, 0.f};
        #pragma unroll
        for (int ks = 0; ks < 3; ++ks) {
            short8 b2f8 = *reinterpret_cast<const short8*>(
                &w2t[g * 104 + ks * 32 + lk8]);
            acc = __builtin_amdgcn_mfma_f32_16x16x32_bf16(a2[ks], b2f8, acc, 0, 0, 0);
        }
        #pragma unroll
        for (int r = 0; r < 4; ++r)
            vsum[r] += fmaxf(acc[r] + bb, 0.f) * wf;
    }
    #pragma unroll
    for (int r = 0; r < 4; ++r) {
        vsum[r] += __shfl_xor(vsum[r], 1);
        vsum[r] += __shfl_xor(vsum[r], 2);
        vsum[r] += __shfl_xor(vsum[r], 4);
        vsum[r] += __shfl_xor(vsum[r], 8);
    }
    if (lrow == 0) {
        #pragma unroll
        for (int r = 0; r < 4; ++r) {
            int btR = bt0 + wv * 16 + rb + r;
            int bR = btR / T;
            int tR = btR - bR * T;
            sc[bR * 256 + tR] = (vsum[r] + bfc0) * 0.125f;
        }
    }
}

// ---------------- softmax + weighted key sum (bf16 keys from kbuf) ----------------
__global__ __launch_bounds__(256)
void attn_out_kernel(const int* __restrict__ keys_length,
                     const float* __restrict__ sc,
                     const unsigned short* __restrict__ kbuf,
                     float* __restrict__ out)
{
    __shared__ float sS[256];
    __shared__ float sRed[8];
    __shared__ float sOutp[4][64];
    const int b = blockIdx.x;
    const int tid = threadIdx.x;
    const int wv = tid >> 6, ln = tid & 63;
    const int len = keys_length[b];

    float s = -INFINITY;
    if (tid < len) s = sc[b * 256 + tid];
    float m = s;
    #pragma unroll
    for (int off = 32; off > 0; off >>= 1) m = fmaxf(m, __shfl_xor(m, off));
    if (ln == 0) sRed[wv] = m;
    __syncthreads();
    float mx = fmaxf(fmaxf(sRed[0], sRed[1]), fmaxf(sRed[2], sRed[3]));
    float e = (tid < len) ? __expf(s - mx) : 0.f;
    sS[tid] = e;
    float sum = e;
    #pragma unroll
    for (int off = 32; off > 0; off >>= 1) sum += __shfl_xor(sum, off);
    if (ln == 0) sRed[4 + wv] = sum;
    __syncthreads();
    float denom = (sRed[4] + sRed[5]) + (sRed[6] + sRed[7]);
    float inv = 1.f / denom;

    const unsigned short* kbu = kbuf + (size_t)b * T * 64;
    const int c = tid & 7;          // 8-bf16 chunk (h = c*8 .. c*8+7)
    const int rg = tid >> 3;        // 0..31 row group
    float acc[8];
    #pragma unroll
    for (int j = 0; j < 8; ++j) acc[j] = 0.f;
    #pragma unroll
    for (int k = 0; k < 7; ++k) {
        int t = rg + (k << 5);
        if (t < T) {
            float w = sS[t];
            uint4 v = *reinterpret_cast<const uint4*>(&kbu[t * 64 + c * 8]);
            acc[0] += w * b2f((unsigned short)(v.x & 0xffff));
            acc[1] += w * b2f((unsigned short)(v.x >> 16));
            acc[2] += w * b2f((unsigned short)(v.y & 0xffff));
            acc[3] += w * b2f((unsigned short)(v.y >> 16));
            acc[4] += w * b2f((unsigned short)(v.z & 0xffff));
            acc[5] += w * b2f((unsigned short)(v.z >> 16));
            acc[6] += w * b2f((unsigned short)(v.w & 0xffff));
            acc[7] += w * b2f((unsigned short)(v.w >> 16));
        }
    }
    #pragma unroll
    for (int j = 0; j < 8; ++j) {
        acc[j] += __shfl_xor(acc[j], 8);
        acc[j] += __shfl_xor(acc[j], 16);
        acc[j] += __shfl_xor(acc[j], 32);
    }
    if (ln < 8) {
        float4 v0, v1;
        v0.x = acc[0]; v0.y = acc[1]; v0.z = acc[2]; v0.w = acc[3];
        v1.x = acc[4]; v1.y = acc[5]; v1.z = acc[6]; v1.w = acc[7];
        *reinterpret_cast<float4*>(&sOutp[wv][ln * 8])     = v0;
        *reinterpret_cast<float4*>(&sOutp[wv][ln * 8 + 4]) = v1;
    }
    __syncthreads();
    if (tid < H) {
        float o = (sOutp[0][tid] + sOutp[1][tid]) + (sOutp[2][tid] + sOutp[3][tid]);
        out[(size_t)b * H + tid] = o * inv;
    }
}

extern "C" void kernel_launch(void* const* d_in, const int* in_sizes, int n_in,
                              void* d_out, int out_size, void* d_ws, size_t ws_size,
                              hipStream_t stream) {
    const float* query       = (const float*)d_in[0];
    const float* keys        = (const float*)d_in[1];
    const int*   keys_length = (const int*)  d_in[2];
    const float* W1          = (const float*)d_in[3];
    const float* b1          = (const float*)d_in[4];
    const float* W2          = (const float*)d_in[5];
    const float* b2          = (const float*)d_in[6];
    const float* Wfc         = (const float*)d_in[7];
    const float* bfc         = (const float*)d_in[8];
    float* out = (float*)d_out;
    char*  wsb = (char*)d_ws;

    unsigned short* w1p  = (unsigned short*)(wsb);             // 20480 B
    unsigned short* w2t  = (unsigned short*)(wsb + 20480);     //  9984 B
    float*          qh   = (float*)         (wsb + 30464);     // 655360 B
    float*          sc   = (float*)         (wsb + 685824);    // 2097152 B
    unsigned short* kbuf = (unsigned short*)(wsb + 2782976);   // 52428800 B

    prep_kernel<<<640, 256, 0, stream>>>(W1, W2, b1, query, w1p, w2t, qh);
    score_kernel<<<NBLK, 512, 0, stream>>>(query, keys, b2, Wfc, bfc,
                                           w1p, w2t, qh, sc, kbuf);
    attn_out_kernel<<<BB, 256, 0, stream>>>(keys_length, sc, kbuf, out);
}